// Round 9
// baseline (11.569 us; speedup 1.0000x reference)
//
#include <hip/hip_runtime.h>
#include <math.h>

#define NH 32   // modes (N/2)

typedef _Float16 f16;
typedef _Float16 f16x2 __attribute__((ext_vector_type(2)));
typedef _Float16 f16x4 __attribute__((ext_vector_type(4)));
typedef float    f32x4 __attribute__((ext_vector_type(4)));

// Reduce x mod 2*pi to [-pi, pi], 2-term float Cody-Waite.
// PI2_HI = 6.28125 (8-bit mantissa) -> k*PI2_HI exact for k < 2^16.
__device__ __forceinline__ float reduce2pi(float x) {
    const float INV2PI = 0.15915494309189535f;
    const float PI2_HI = 6.28125f;
    const float PI2_LO = 1.9353071795864769e-3f;
    float k = rintf(x * INV2PI);
    float r = fmaf(-k, PI2_HI, x);
    r = fmaf(-k, PI2_LO, r);
    return r;
}

// Vandermonde-factored S4D: l = 128a + b (a<32, b<128)
//   K[h,l] = sum_n Re(G[n,a] * W[n,b]),  G = c_eff*u^a (u=z^128), W = z^b
// R9: TWO blocks per h, each covering 64 b-columns -> grid 2048 = 8 blocks/CU
// (32 waves/CU, full thread occupancy; R7/R8 ran at 16 waves/CU and were
// latency-bound: three throughput fixes in R8 gave exactly 0 delta).
// Matmul D[b][a] = sum_k X[b][k]*Y[k][a], k interleaved complex
// (k=2n -> Wr,Gr; k=2n+1 -> Wi,-Gi). Fragment mappings validated R7/R8
// (absmax at f16-rounding level). Lane's 4 acc regs = 4 consecutive b =
// 4 consecutive output floats -> global_store_dwordx4.
__global__ __launch_bounds__(256, 4) void s4d_kernel(
    const float* __restrict__ log_dt,
    const float* __restrict__ Cv,          // (H, 32, 2)
    const float* __restrict__ log_A_real,  // (H, 32)
    const float* __restrict__ A_imag,      // (H, 32)
    float* __restrict__ Kout,              // (H, L), L = 4096
    int L)
{
    const int bid = blockIdx.x;
    const int h   = bid >> 1;
    const int blk = bid & 1;         // b-range [64*blk, 64*blk + 64)
    const int tid = threadIdx.x;

    // pitch 68 f16 (136 B): 8B-aligned rows for f16x4 reads; fragment
    // reads land on 16 even banks (4-way, ~1.6x on 8+8 reads - negligible).
    __shared__ f16 Alds[32][68];     // Y: [a][k]  k=2n -> Gr, k=2n+1 -> -Gi
    __shared__ f16 Wlds[64][68];     // X: [b_local][k]  k=2n -> Wr, 2n+1 -> Wi
    __shared__ float s_dar[NH], s_dai[NH];
    __shared__ float s_zr[NH],  s_zi[NH];    // z = exp(dtA)
    __shared__ float s_ur[NH],  s_ui[NH];    // u = z^128
    __shared__ float s_cer[NH], s_cei[NH];   // c_eff (x2 folded)
    __shared__ float s_e1r[NH], s_e1i[NH];   // z^1024
    __shared__ float s_e2r[NH], s_e2i[NH];   // z^2048

    // ---- Phase A: 128 threads; thread (n, j) does ONE exp+sincos chain ----
    if (tid < 128) {
        const int n = tid & 31;
        const int j = tid >> 5;              // 0:z(+c_eff) 1:u 2:e1 3:e2
        const float dt  = __expf(log_dt[h]);
        const float Ar  = -__expf(log_A_real[h * NH + n]);
        const float Ai  = A_imag[h * NH + n];
        const float dar = Ar * dt;
        const float dai = Ai * dt;
        const float S = (j == 0) ? 1.0f : (j == 1) ? 128.0f
                      : (j == 2) ? 1024.0f : 2048.0f;   // all exact scalings
        float e = __expf(dar * S);           // may underflow to 0: mode dead
        float sn, cs;
        __sincosf(reduce2pi(dai * S), &sn, &cs);
        float vr = e * cs, vi = e * sn;
        if (j == 0) {
            s_dar[n] = dar;  s_dai[n] = dai;
            s_zr[n] = vr;    s_zi[n] = vi;
            // c_eff = 2 * C * (z - 1)/A
            float edr = vr - 1.0f, edi = vi;
            float inv = 1.0f / fmaf(Ar, Ar, Ai * Ai);
            float fr  = (edr * Ar + edi * Ai) * inv;
            float fi  = (edi * Ar - edr * Ai) * inv;
            float cr  = Cv[(h * NH + n) * 2 + 0];
            float ci  = Cv[(h * NH + n) * 2 + 1];
            s_cer[n] = 2.0f * (cr * fr - ci * fi);
            s_cei[n] = 2.0f * (cr * fi + ci * fr);
        } else if (j == 1) { s_ur[n]  = vr;  s_ui[n]  = vi; }
        else if   (j == 2) { s_e1r[n] = vr;  s_e1i[n] = vi; }
        else               { s_e2r[n] = vr;  s_e2i[n] = vi; }
    }
    __syncthreads();

    const int lane = tid & 63;
    const int wv   = tid >> 6;       // wave id 0..3

    // ---- G build: wave wv fills rows a = 8wv..8wv+7 (lanes 0..31) ----
    if (lane < NH) {
        const int n = lane;
        float sr, si;                // seed = u^(8wv) from exact components
        if      (wv == 0) { sr = 1.0f;      si = 0.0f; }
        else if (wv == 1) { sr = s_e1r[n];  si = s_e1i[n]; }
        else if (wv == 2) { sr = s_e2r[n];  si = s_e2i[n]; }
        else {
            sr = s_e2r[n] * s_e1r[n] - s_e2i[n] * s_e1i[n];
            si = s_e2r[n] * s_e1i[n] + s_e2i[n] * s_e1r[n];
        }
        float gr = s_cer[n] * sr - s_cei[n] * si;
        float gi = s_cer[n] * si + s_cei[n] * sr;
        const float ur = s_ur[n], ui = s_ui[n];
        #pragma unroll
        for (int s = 0; s < 8; ++s) {
            const int a = wv * 8 + s;
            f16x2 pg = { (f16)gr, (f16)(-gi) };
            *reinterpret_cast<f16x2*>(&Alds[a][2 * n]) = pg;
            float t = gr * ur - gi * ui;     // g *= u
            gi = gr * ui + gi * ur;
            gr = t;
        }
    }

    // ---- W build: thread = (mode n, 8 consecutive b in this block's range) ----
    {
        const int n  = tid & 31;
        const int bg = tid >> 5;                 // 0..7
        const int b0 = blk * 64 + bg * 8;
        const float b0f = (float)b0;             // <= 120
        float e0 = __expf(s_dar[n] * b0f);
        float sn, cs;
        __sincosf(s_dai[n] * b0f, &sn, &cs);     // |ang| <= ~1180 rad (R2-R8 regime)
        float wr = e0 * cs, wi = e0 * sn;        // W(n, b0)
        const float zr = s_zr[n], zi = s_zi[n];
        #pragma unroll
        for (int i = 0; i < 8; ++i) {
            const int bl = bg * 8 + i;           // local b row
            f16x2 pw = { (f16)wr, (f16)wi };
            *reinterpret_cast<f16x2*>(&Wlds[bl][2 * n]) = pw;
            float t = wr * zr - wi * zi;         // w *= z
            wi = wr * zi + wi * zr;
            wr = t;
        }
    }
    __syncthreads();

    // ---- MFMA + direct vectorized store ----
    // X-frag: lane holds X[b_local = 16wv + (l&15)][k = 16ks + 4(l>>4) + j]
    // Y-frag: lane holds Y[k = 16ks + 4(l>>4) + j][a = 16ni + (l&15)]
    // D:      lane holds D[b_local = 16wv + 4(l>>4)+reg][a = 16ni + (l&15)]
    // l_out = 128a + 64blk + b_local -> 4 acc regs are consecutive floats.
    const int r = lane & 15;
    const int q = lane >> 4;
    float* outp = Kout + (size_t)h * (size_t)L + blk * 64;
    #pragma unroll
    for (int ni = 0; ni < 2; ++ni) {
        f32x4 acc = {0.f, 0.f, 0.f, 0.f};
        #pragma unroll
        for (int ks = 0; ks < 4; ++ks) {
            f16x4 xf = *(const f16x4*)&Wlds[16 * wv + r][16 * ks + 4 * q];
            f16x4 yf = *(const f16x4*)&Alds[16 * ni + r][16 * ks + 4 * q];
            acc = __builtin_amdgcn_mfma_f32_16x16x16f16(xf, yf, acc, 0, 0, 0);
        }
        const int a  = 16 * ni + r;
        const int bl = 16 * wv + 4 * q;
        *(f32x4*)&outp[(size_t)a * 128 + bl] = acc;
    }
}

extern "C" void kernel_launch(void* const* d_in, const int* in_sizes, int n_in,
                              void* d_out, int out_size, void* d_ws, size_t ws_size,
                              hipStream_t stream) {
    // inputs: [0]=L (int scalar), [1]=log_dt (H,), [2]=C (H,32,2),
    //         [3]=log_A_real (H,32), [4]=A_imag (H,32)
    const float* log_dt     = (const float*)d_in[1];
    const float* Cv         = (const float*)d_in[2];
    const float* log_A_real = (const float*)d_in[3];
    const float* A_imag     = (const float*)d_in[4];
    float* Kout = (float*)d_out;

    const int Hn = in_sizes[1];          // 1024
    const int L  = out_size / Hn;        // 4096 (tiling assumes this)

    dim3 grid(Hn * 2), block(256);
    hipLaunchKernelGGL(s4d_kernel, grid, block, 0, stream,
                       log_dt, Cv, log_A_real, A_imag, Kout, L);
}

// Round 10
// 10.623 us; speedup vs baseline: 1.0891x; 1.0891x over previous
//
#include <hip/hip_runtime.h>
#include <math.h>

#define NH 32   // modes (N/2)

typedef _Float16 f16;
typedef _Float16 f16x2 __attribute__((ext_vector_type(2)));
typedef _Float16 f16x4 __attribute__((ext_vector_type(4)));
typedef float    f32x2 __attribute__((ext_vector_type(2)));
typedef float    f32x4 __attribute__((ext_vector_type(4)));

// Reduce x mod 2*pi to [-pi, pi], 2-term float Cody-Waite.
// PI2_HI = 6.28125 (8-bit mantissa) -> k*PI2_HI exact for k < 2^16.
__device__ __forceinline__ float reduce2pi(float x) {
    const float INV2PI = 0.15915494309189535f;
    const float PI2_HI = 6.28125f;
    const float PI2_LO = 1.9353071795864769e-3f;
    float k = rintf(x * INV2PI);
    float r = fmaf(-k, PI2_HI, x);
    r = fmaf(-k, PI2_LO, r);
    return r;
}

// Vandermonde-factored S4D: l = 128a + b (a<32, b<128)
//   K[h,l] = sum_n Re(G[n,a] * W[n,b]),  G = c_eff*u^a (u=z^128), W = z^b
// One block per h. Matmul D[b][a] = sum_k X[b][k]*Y[k][a], k interleaved
// complex (k=2n -> Wr,Gr; k=2n+1 -> Wi,-Gi); fragment mappings validated
// R7/R8 (absmax at f16-rounding level).
// R10: epilogue stages D in LDS then stores FULL 512-B rows per wave
// instruction (lane l -> out[a*128 + 2l], f32x2, nontemporal) - removes the
// 64-B-chunk scatter of R7-R9 to test whether the 11.3 us plateau is
// write-path (H1) or a fixed per-replay floor (H2).
__global__ __launch_bounds__(256, 4) void s4d_kernel(
    const float* __restrict__ log_dt,
    const float* __restrict__ Cv,          // (H, 32, 2)
    const float* __restrict__ log_A_real,  // (H, 32)
    const float* __restrict__ A_imag,      // (H, 32)
    float* __restrict__ Kout,              // (H, L), L = 4096
    int L)
{
    const int h   = blockIdx.x;
    const int tid = threadIdx.x;

    __shared__ f16 Alds[32][68];     // Y: [a][k]  k=2n -> Gr, k=2n+1 -> -Gi
    __shared__ f16 Wlds[128][68];    // X: [b][k]  k=2n -> Wr, k=2n+1 -> Wi
    __shared__ float s_out[32][132]; // staged D[a][b]; +4 pad (2-way reads)
    __shared__ float s_dar[NH], s_dai[NH];
    __shared__ float s_zr[NH],  s_zi[NH];    // z = exp(dtA)
    __shared__ float s_ur[NH],  s_ui[NH];    // u = z^128
    __shared__ float s_cer[NH], s_cei[NH];   // c_eff (x2 folded)
    __shared__ float s_e1r[NH], s_e1i[NH];   // z^1024
    __shared__ float s_e2r[NH], s_e2i[NH];   // z^2048

    // ---- Phase A: 128 threads; thread (n, j) does ONE exp+sincos chain ----
    if (tid < 128) {
        const int n = tid & 31;
        const int j = tid >> 5;              // 0:z(+c_eff) 1:u 2:e1 3:e2
        const float dt  = __expf(log_dt[h]);
        const float Ar  = -__expf(log_A_real[h * NH + n]);
        const float Ai  = A_imag[h * NH + n];
        const float dar = Ar * dt;
        const float dai = Ai * dt;
        const float S = (j == 0) ? 1.0f : (j == 1) ? 128.0f
                      : (j == 2) ? 1024.0f : 2048.0f;   // all exact scalings
        float e = __expf(dar * S);           // may underflow to 0: mode dead
        float sn, cs;
        __sincosf(reduce2pi(dai * S), &sn, &cs);
        float vr = e * cs, vi = e * sn;
        if (j == 0) {
            s_dar[n] = dar;  s_dai[n] = dai;
            s_zr[n] = vr;    s_zi[n] = vi;
            // c_eff = 2 * C * (z - 1)/A
            float edr = vr - 1.0f, edi = vi;
            float inv = 1.0f / fmaf(Ar, Ar, Ai * Ai);
            float fr  = (edr * Ar + edi * Ai) * inv;
            float fi  = (edi * Ar - edr * Ai) * inv;
            float cr  = Cv[(h * NH + n) * 2 + 0];
            float ci  = Cv[(h * NH + n) * 2 + 1];
            s_cer[n] = 2.0f * (cr * fr - ci * fi);
            s_cei[n] = 2.0f * (cr * fi + ci * fr);
        } else if (j == 1) { s_ur[n]  = vr;  s_ui[n]  = vi; }
        else if   (j == 2) { s_e1r[n] = vr;  s_e1i[n] = vi; }
        else               { s_e2r[n] = vr;  s_e2i[n] = vi; }
    }
    __syncthreads();

    const int lane = tid & 63;
    const int wv   = tid >> 6;       // wave id 0..3

    // ---- G build: wave wv fills rows a = 8wv..8wv+7 (lanes 0..31) ----
    if (lane < NH) {
        const int n = lane;
        float sr, si;                // seed = u^(8wv) from exact components
        if      (wv == 0) { sr = 1.0f;      si = 0.0f; }
        else if (wv == 1) { sr = s_e1r[n];  si = s_e1i[n]; }
        else if (wv == 2) { sr = s_e2r[n];  si = s_e2i[n]; }
        else {
            sr = s_e2r[n] * s_e1r[n] - s_e2i[n] * s_e1i[n];
            si = s_e2r[n] * s_e1i[n] + s_e2i[n] * s_e1r[n];
        }
        float gr = s_cer[n] * sr - s_cei[n] * si;
        float gi = s_cer[n] * si + s_cei[n] * sr;
        const float ur = s_ur[n], ui = s_ui[n];
        #pragma unroll
        for (int s = 0; s < 8; ++s) {
            const int a = wv * 8 + s;
            f16x2 pg = { (f16)gr, (f16)(-gi) };
            *reinterpret_cast<f16x2*>(&Alds[a][2 * n]) = pg;
            float t = gr * ur - gi * ui;     // g *= u
            gi = gr * ui + gi * ur;
            gr = t;
        }
    }

    // ---- W build: thread = (mode n, 16 consecutive b) ----
    {
        const int n  = tid & 31;
        const int bg = tid >> 5;                 // 0..7
        const float b0f = (float)(bg * 16);
        float e0 = __expf(s_dar[n] * b0f);
        float sn, cs;
        __sincosf(s_dai[n] * b0f, &sn, &cs);     // |ang| <= ~1100 rad (R2-R9)
        float wr = e0 * cs, wi = e0 * sn;        // W(n, b0)
        const float zr = s_zr[n], zi = s_zi[n];
        #pragma unroll
        for (int i = 0; i < 16; ++i) {
            const int b = bg * 16 + i;
            f16x2 pw = { (f16)wr, (f16)wi };
            *reinterpret_cast<f16x2*>(&Wlds[b][2 * n]) = pw;
            float t = wr * zr - wi * zi;         // w *= z
            wi = wr * zi + wi * zr;
            wr = t;
        }
    }
    __syncthreads();

    // ---- MFMA -> stage D in LDS ----
    // X-frag: lane holds X[b = 32wv+16mi + (l&15)][k = 16ks + 4(l>>4) + j]
    // Y-frag: lane holds Y[k = 16ks + 4(l>>4) + j][a = 16ni + (l&15)]
    // D:      lane holds D[b = 32wv+16mi + 4(l>>4)+reg][a = 16ni + (l&15)]
    const int r = lane & 15;
    const int q = lane >> 4;
    #pragma unroll
    for (int mi = 0; mi < 2; ++mi) {
        #pragma unroll
        for (int ni = 0; ni < 2; ++ni) {
            f32x4 acc = {0.f, 0.f, 0.f, 0.f};
            #pragma unroll
            for (int ks = 0; ks < 4; ++ks) {
                f16x4 xf = *(const f16x4*)&Wlds[32 * wv + 16 * mi + r][16 * ks + 4 * q];
                f16x4 yf = *(const f16x4*)&Alds[16 * ni + r][16 * ks + 4 * q];
                acc = __builtin_amdgcn_mfma_f32_16x16x16f16(xf, yf, acc, 0, 0, 0);
            }
            const int a  = 16 * ni + r;
            const int b0 = 32 * wv + 16 * mi + 4 * q;   // 16-B aligned
            *(f32x4*)&s_out[a][b0] = acc;
        }
    }
    __syncthreads();

    // ---- Epilogue: full-row coalesced nontemporal stores ----
    // Wave wv stores rows a = 8wv..8wv+7; lane l -> out[a*128 + 2l] (f32x2).
    // One wave instruction = 64 lanes x 8 B = 512 B contiguous (4 full lines).
    float* outp = Kout + (size_t)h * (size_t)L;
    #pragma unroll
    for (int s = 0; s < 8; ++s) {
        const int a = wv * 8 + s;
        f32x2 v = *(const f32x2*)&s_out[a][2 * lane];
        __builtin_nontemporal_store(v, (f32x2*)&outp[(size_t)a * 128 + 2 * lane]);
    }
}

extern "C" void kernel_launch(void* const* d_in, const int* in_sizes, int n_in,
                              void* d_out, int out_size, void* d_ws, size_t ws_size,
                              hipStream_t stream) {
    // inputs: [0]=L (int scalar), [1]=log_dt (H,), [2]=C (H,32,2),
    //         [3]=log_A_real (H,32), [4]=A_imag (H,32)
    const float* log_dt     = (const float*)d_in[1];
    const float* Cv         = (const float*)d_in[2];
    const float* log_A_real = (const float*)d_in[3];
    const float* A_imag     = (const float*)d_in[4];
    float* Kout = (float*)d_out;

    const int Hn = in_sizes[1];          // 1024
    const int L  = out_size / Hn;        // 4096 (tiling assumes this)

    dim3 grid(Hn), block(256);
    hipLaunchKernelGGL(s4d_kernel, grid, block, 0, stream,
                       log_dt, Cv, log_A_real, A_imag, Kout, L);
}

// Round 11
// 10.063 us; speedup vs baseline: 1.1497x; 1.0557x over previous
//
#include <hip/hip_runtime.h>
#include <math.h>

#define NH 32   // modes (N/2)

typedef _Float16 f16;
typedef _Float16 f16x2 __attribute__((ext_vector_type(2)));
typedef _Float16 f16x4 __attribute__((ext_vector_type(4)));
typedef float    f32x4 __attribute__((ext_vector_type(4)));

// Reduce x mod 2*pi to [-pi, pi], 2-term float Cody-Waite.
// PI2_HI = 6.28125 (8-bit mantissa) -> k*PI2_HI exact for k < 2^16
// (covers |x| <= ~3e4 here; k <= ~4800). Error ~1e-6 rad.
__device__ __forceinline__ float reduce2pi(float x) {
    const float INV2PI = 0.15915494309189535f;
    const float PI2_HI = 6.28125f;
    const float PI2_LO = 1.9353071795864769e-3f;
    float k = rintf(x * INV2PI);
    float r = fmaf(-k, PI2_HI, x);
    r = fmaf(-k, PI2_LO, r);
    return r;
}

// Vandermonde-factored S4D: l = 128a + b (a<32, b<128)
//   K[h,l] = sum_n Re(G[n,a] * W[n,b]),  G = c_eff*u^a (u=z^128), W = z^b
// One block per h. Matmul D[b][a] = sum_k X[b][k]*Y[k][a], k interleaved
// complex (k=2n -> Wr,Gr; k=2n+1 -> Wi,-Gi); fragment mappings validated
// R7-R10 (absmax at f16-rounding level).
// R11: NO phase A - every build thread computes its own per-mode constants
// (redundant parallel HW-trans work instead of a staged serial phase), so
// there is exactly ONE barrier before MFMA and one before the epilogue.
// Epilogue stores f32x4 (1 KB per wave instruction, nontemporal).
__global__ __launch_bounds__(256, 4) void s4d_kernel(
    const float* __restrict__ log_dt,
    const float* __restrict__ Cv,          // (H, 32, 2)
    const float* __restrict__ log_A_real,  // (H, 32)
    const float* __restrict__ A_imag,      // (H, 32)
    float* __restrict__ Kout,              // (H, L), L = 4096
    int L)
{
    const int h    = blockIdx.x;
    const int tid  = threadIdx.x;
    const int lane = tid & 63;
    const int wv   = tid >> 6;       // wave id 0..3

    __shared__ f16 Alds[32][68];     // Y: [a][k]  k=2n -> Gr, k=2n+1 -> -Gi
    __shared__ f16 Wlds[128][68];    // X: [b][k]  k=2n -> Wr, k=2n+1 -> Wi
    __shared__ float s_out[32][132]; // staged D[a][b]; pitch 132 (528 B, 16B-mult)

    // ---- W build: all 256 threads; thread = (mode n, 16 consecutive b) ----
    // Each thread computes its own dtA and z (parallel HW trans, no staging).
    {
        const int n  = tid & 31;
        const int bg = tid >> 5;                 // 0..7
        const float dt  = __expf(log_dt[h]);
        const float Ar  = -__expf(log_A_real[h * NH + n]);
        const float Ai  = A_imag[h * NH + n];
        const float dar = Ar * dt;
        const float dai = Ai * dt;
        float zr, zi;
        {
            float e = __expf(dar);
            float sn, cs; __sincosf(dai, &sn, &cs);   // |dai| <= ~9.8
            zr = e * cs;  zi = e * sn;
        }
        const float b0f = (float)(bg * 16);
        float e0 = __expf(dar * b0f);
        float sn, cs; __sincosf(reduce2pi(dai * b0f), &sn, &cs);
        float wr = e0 * cs, wi = e0 * sn;        // W(n, b0)
        #pragma unroll
        for (int i = 0; i < 16; ++i) {
            const int b = bg * 16 + i;
            f16x2 pw = { (f16)wr, (f16)wi };
            *reinterpret_cast<f16x2*>(&Wlds[b][2 * n]) = pw;
            float t = wr * zr - wi * zi;         // w *= z
            wi = wr * zi + wi * zr;
            wr = t;
        }
    }

    // ---- G build: lanes 0..31 of wave wv fill rows a = 8wv..8wv+7 ----
    if (lane < NH) {
        const int n = lane;
        const float dt  = __expf(log_dt[h]);
        const float Ar  = -__expf(log_A_real[h * NH + n]);
        const float Ai  = A_imag[h * NH + n];
        const float dar = Ar * dt;
        const float dai = Ai * dt;
        float zr, zi;
        {
            float e = __expf(dar);
            float sn, cs; __sincosf(dai, &sn, &cs);
            zr = e * cs;  zi = e * sn;
        }
        // c_eff = 2 * C * (z - 1)/A
        float edr = zr - 1.0f, edi = zi;
        float inv = 1.0f / fmaf(Ar, Ar, Ai * Ai);
        float fr  = (edr * Ar + edi * Ai) * inv;
        float fi  = (edi * Ar - edr * Ai) * inv;
        float cr  = Cv[(h * NH + n) * 2 + 0];
        float ci  = Cv[(h * NH + n) * 2 + 1];
        float cer = 2.0f * (cr * fr - ci * fi);
        float cei = 2.0f * (cr * fi + ci * fr);
        // u = z^128 (exact scaling)
        float eu = __expf(dar * 128.0f);
        float su, cu; __sincosf(reduce2pi(dai * 128.0f), &su, &cu);
        float ur = eu * cu, ui = eu * su;
        // seed = z^(1024*wv); 1024 exact, x3 one rounding; may underflow->0
        const float S = (float)(1024 * wv);
        float es = __expf(dar * S);
        float ss, sc; __sincosf(reduce2pi(dai * S), &ss, &sc);
        float br = es * sc, bi = es * ss;
        float gr = cer * br - cei * bi;
        float gi = cer * bi + cei * br;
        #pragma unroll
        for (int s = 0; s < 8; ++s) {
            const int a = wv * 8 + s;
            f16x2 pg = { (f16)gr, (f16)(-gi) };
            *reinterpret_cast<f16x2*>(&Alds[a][2 * n]) = pg;
            float t = gr * ur - gi * ui;         // g *= u
            gi = gr * ui + gi * ur;
            gr = t;
        }
    }
    __syncthreads();

    // ---- MFMA -> stage D in LDS ----
    // X-frag: lane holds X[b = 32wv+16mi + (l&15)][k = 16ks + 4(l>>4) + j]
    // Y-frag: lane holds Y[k = 16ks + 4(l>>4) + j][a = 16ni + (l&15)]
    // D:      lane holds D[b = 32wv+16mi + 4(l>>4)+reg][a = 16ni + (l&15)]
    const int r = lane & 15;
    const int q = lane >> 4;
    #pragma unroll
    for (int mi = 0; mi < 2; ++mi) {
        #pragma unroll
        for (int ni = 0; ni < 2; ++ni) {
            f32x4 acc = {0.f, 0.f, 0.f, 0.f};
            #pragma unroll
            for (int ks = 0; ks < 4; ++ks) {
                f16x4 xf = *(const f16x4*)&Wlds[32 * wv + 16 * mi + r][16 * ks + 4 * q];
                f16x4 yf = *(const f16x4*)&Alds[16 * ni + r][16 * ks + 4 * q];
                acc = __builtin_amdgcn_mfma_f32_16x16x16f16(xf, yf, acc, 0, 0, 0);
            }
            const int a  = 16 * ni + r;
            const int b0 = 32 * wv + 16 * mi + 4 * q;   // 16-B aligned
            *(f32x4*)&s_out[a][b0] = acc;
        }
    }
    __syncthreads();

    // ---- Epilogue: full-row coalesced nontemporal f32x4 stores ----
    // Wave wv stores rows a = 8wv..8wv+7, two rows per instruction:
    // lane l -> row a + (l>>5), cols (l&31)*4 .. +3. 64 lanes x 16 B = 1 KB.
    float* outp = Kout + (size_t)h * (size_t)L;
    #pragma unroll
    for (int s = 0; s < 4; ++s) {
        const int a = wv * 8 + 2 * s + (lane >> 5);
        const int c = (lane & 31) * 4;
        f32x4 v = *(const f32x4*)&s_out[a][c];
        __builtin_nontemporal_store(v, (f32x4*)&outp[(size_t)a * 128 + c]);
    }
}

extern "C" void kernel_launch(void* const* d_in, const int* in_sizes, int n_in,
                              void* d_out, int out_size, void* d_ws, size_t ws_size,
                              hipStream_t stream) {
    // inputs: [0]=L (int scalar), [1]=log_dt (H,), [2]=C (H,32,2),
    //         [3]=log_A_real (H,32), [4]=A_imag (H,32)
    const float* log_dt     = (const float*)d_in[1];
    const float* Cv         = (const float*)d_in[2];
    const float* log_A_real = (const float*)d_in[3];
    const float* A_imag     = (const float*)d_in[4];
    float* Kout = (float*)d_out;

    const int Hn = in_sizes[1];          // 1024
    const int L  = out_size / Hn;        // 4096 (tiling assumes this)

    dim3 grid(Hn), block(256);
    hipLaunchKernelGGL(s4d_kernel, grid, block, 0, stream,
                       log_dt, Cv, log_A_real, A_imag, Kout, L);
}